// Round 16
// baseline (559.237 us; speedup 1.0000x reference)
//
#include <hip/hip_runtime.h>
#include <hip/hip_bf16.h>
#include <math.h>

// ---------------------------------------------------------------------------
// ChunkGatedAttentionUnit: B=2, S=4096, H=1024, D=2048, CHUNK=128, nC=32
// Round 16: R15 base + qkvg on coreHB — A via LDS (triple-buffer, 16KB/buf),
// B (weights, L2-resident) DIRECT global->register, double-buffered 1 K-tile
// ahead. Removes B from LDS: LDS demand 2300->1024 cyc/K-tile < MFMA 1242
// -> MFMA-bound. vmcnt ledger: steady 8 outstanding, vmcnt(2) per half-iter.
// ---------------------------------------------------------------------------

typedef __bf16 bf16_t;
typedef __bf16 bf16x8 __attribute__((ext_vector_type(8)));
typedef __bf16 bf16x4 __attribute__((ext_vector_type(4)));
typedef float f32x4 __attribute__((ext_vector_type(4)));

#define NB_ 2
#define SEQ 4096
#define HID 1024
#define DD 2048
#define BS 8192
#define LDS_TB 73728    // coreTB: 3 x 24KB buffers
#define LDS_HB 69632    // coreHB: 3 x 16KB A-buffers (49152) < staging 69632

__device__ __forceinline__ void async16(const void* g, void* l) {
  __builtin_amdgcn_global_load_lds(
      (const __attribute__((address_space(1))) void*)g,
      (__attribute__((address_space(3))) void*)l, 16, 0, 0);
}

#define VMW(n) asm volatile("s_waitcnt vmcnt(" #n ")" ::: "memory")
#define VMW0 asm volatile("s_waitcnt vmcnt(0)" ::: "memory")
#define BARR __builtin_amdgcn_s_barrier()
#define FEN asm volatile("" ::: "memory")

// ===== coreTB<WM,WN> (R12): BK=32 triple-buffer, counted vmcnt ==============
template <int WM, int WN>
__device__ __forceinline__ void coreTB(const bf16_t* __restrict__ A, int lda,
                                       const bf16_t* __restrict__ B, int ldb, int nt,
                                       bf16_t* lds, f32x4 (&acc)[4][4]) {
  constexpr int T = WM * WN * 64;
  constexpr int AE = WM * 64 * 32;
  constexpr int BUF = AE + WN * 64 * 32;
  constexpr int NISS = BUF / (T * 8);
  const int t = threadIdx.x;
  const int lane = t & 63, w = t >> 6;
  const int wm = w / WN, wn = w % WN;
  const int lr = lane & 15, lg = lane >> 4;

  int aOff[4], bOff[4];
#pragma unroll
  for (int f = 0; f < 4; ++f) {
    int ra = wm * 64 + f * 16 + lr;
    aOff[f] = ra * 32 + (((lg + (ra >> 1)) & 3) << 3);
    int rb = wn * 64 + f * 16 + lr;
    bOff[f] = AE + rb * 32 + (((lg + (rb >> 1)) & 3) << 3);
  }
  int src[NISS];
#pragma unroll
  for (int q = 0; q < NISS; ++q) {
    int e = q * T * 8 + t * 8;
    bool isB = (q * T * 8) >= AE;
    int e2 = isB ? e - AE : e;
    int r = e2 >> 5;
    int g = (((e2 >> 3) & 3) - (r >> 1)) & 3;
    src[q] = r * (isB ? ldb : lda) + g * 8;
  }
#pragma unroll
  for (int m = 0; m < 4; ++m)
#pragma unroll
    for (int n = 0; n < 4; ++n) acc[m][n] = (f32x4){0.f, 0.f, 0.f, 0.f};

#pragma unroll
  for (int q = 0; q < NISS; ++q) {
    bool isB = (q * T * 8) >= AE;
    async16((isB ? B : A) + src[q], lds + q * T * 8 + t * 8);
  }
  {
    const int k1 = (1 < nt ? 1 : 0) << 5;
#pragma unroll
    for (int q = 0; q < NISS; ++q) {
      bool isB = (q * T * 8) >= AE;
      async16((isB ? B : A) + k1 + src[q], lds + BUF + q * T * 8 + t * 8);
    }
  }

  for (int tt = 0; tt < nt; ++tt) {
    bf16_t* cur = lds + (tt % 3) * BUF;
    bf16_t* nxt = lds + ((tt + 2) % 3) * BUF;
    const int kn = (tt + 2 < nt ? tt + 2 : 0) << 5;
    if constexpr (NISS == 3) {
      asm volatile("s_waitcnt vmcnt(3)" ::: "memory");
    } else if constexpr (NISS == 4) {
      asm volatile("s_waitcnt vmcnt(4)" ::: "memory");
    } else {
      asm volatile("s_waitcnt vmcnt(0)" ::: "memory");
    }
    BARR; FEN;
    bf16x8 af[4], bv[4];
#pragma unroll
    for (int f = 0; f < 4; ++f) af[f] = *reinterpret_cast<const bf16x8*>(&cur[aOff[f]]);
#pragma unroll
    for (int f = 0; f < 4; ++f) bv[f] = *reinterpret_cast<const bf16x8*>(&cur[bOff[f]]);
#pragma unroll
    for (int q = 0; q < NISS; ++q) {
      bool isB = (q * T * 8) >= AE;
      async16((isB ? B : A) + kn + src[q], nxt + q * T * 8 + t * 8);
    }
    __builtin_amdgcn_s_setprio(1);
#pragma unroll
    for (int mf = 0; mf < 4; ++mf)
#pragma unroll
      for (int nf = 0; nf < 4; ++nf)
        acc[mf][nf] =
            __builtin_amdgcn_mfma_f32_16x16x32_bf16(af[mf], bv[nf], acc[mf][nf], 0, 0, 0);
    __builtin_amdgcn_s_setprio(0);
  }
  VMW0;
  BARR; FEN;
}

// ===== coreHB (qkvg): 256x128 tile, A via LDS, B direct->reg ================
// 8 waves (4M x 2N), per-wave 64x64. nt must be EVEN.
// Ledger: prologue A0[2],B0[4],A1[2]=8; half-iter: vmcnt(2)+barrier confirms
// {A(tt),B(tt)}, leaves A(tt+1); issue B(tt+1)[4] then A(tt+2)[2] -> 8.
__device__ __forceinline__ void coreHB(const bf16_t* __restrict__ A, int lda,
                                       const bf16_t* __restrict__ B, int ldb, int nt,
                                       bf16_t* lds, f32x4 (&acc)[4][4]) {
  const int t = threadIdx.x, lane = t & 63, w = t >> 6;
  const int wm = w >> 1, wn = w & 1;
  const int lr = lane & 15, lg = lane >> 4;
  int aOff[4];
#pragma unroll
  for (int f = 0; f < 4; ++f) {
    int ra = wm * 64 + f * 16 + lr;
    aOff[f] = ra * 32 + (((lg + (ra >> 1)) & 3) << 3);
  }
  int srcA[2];
#pragma unroll
  for (int q = 0; q < 2; ++q) {
    int e = q * 4096 + t * 8;
    int r = e >> 5;
    int g = (((e >> 3) & 3) - (r >> 1)) & 3;
    srcA[q] = r * lda + g * 8;
  }
  const bf16_t* bp = B + (long)(wn * 64 + lr) * ldb + lg * 8;
#pragma unroll
  for (int m = 0; m < 4; ++m)
#pragma unroll
    for (int n = 0; n < 4; ++n) acc[m][n] = (f32x4){0.f, 0.f, 0.f, 0.f};

  // prologue: A(0)[2], B(0)[4], A(1)[2]
  async16(A + srcA[0], lds + t * 8);
  async16(A + srcA[1], lds + 4096 + t * 8);
  FEN;
  bf16x8 bvA0, bvA1, bvA2, bvA3, bvB0, bvB1, bvB2, bvB3;
  bvA0 = *reinterpret_cast<const bf16x8*>(bp + 0l * 16 * ldb);
  bvA1 = *reinterpret_cast<const bf16x8*>(bp + 1l * 16 * ldb);
  bvA2 = *reinterpret_cast<const bf16x8*>(bp + 2l * 16 * ldb);
  bvA3 = *reinterpret_cast<const bf16x8*>(bp + 3l * 16 * ldb);
  FEN;
  {
    const int k1 = (1 < nt ? 1 : 0) << 5;
    async16(A + k1 + srcA[0], lds + 8192 + t * 8);
    async16(A + k1 + srcA[1], lds + 8192 + 4096 + t * 8);
  }
  FEN;

  for (int tt = 0; tt < nt; tt += 2) {
    // ---- even half: tile tt (A buf tt%3, B in bvA) ----
    VMW(2); BARR; FEN;
    {
      bf16_t* cur = lds + (tt % 3) * 8192;
      const int kB = ((tt + 1 < nt ? tt + 1 : 0) << 5);
      bvB0 = *reinterpret_cast<const bf16x8*>(bp + 0l * 16 * ldb + kB);
      bvB1 = *reinterpret_cast<const bf16x8*>(bp + 1l * 16 * ldb + kB);
      bvB2 = *reinterpret_cast<const bf16x8*>(bp + 2l * 16 * ldb + kB);
      bvB3 = *reinterpret_cast<const bf16x8*>(bp + 3l * 16 * ldb + kB);
      FEN;
      const int kA = ((tt + 2 < nt ? tt + 2 : 0) << 5);
      bf16_t* nA = lds + ((tt + 2) % 3) * 8192;
      async16(A + kA + srcA[0], nA + t * 8);
      async16(A + kA + srcA[1], nA + 4096 + t * 8);
      FEN;
      __builtin_amdgcn_s_setprio(1);
#pragma unroll
      for (int mf = 0; mf < 4; ++mf) {
        bf16x8 af = *reinterpret_cast<const bf16x8*>(&cur[aOff[mf]]);
        acc[mf][0] = __builtin_amdgcn_mfma_f32_16x16x32_bf16(af, bvA0, acc[mf][0], 0, 0, 0);
        acc[mf][1] = __builtin_amdgcn_mfma_f32_16x16x32_bf16(af, bvA1, acc[mf][1], 0, 0, 0);
        acc[mf][2] = __builtin_amdgcn_mfma_f32_16x16x32_bf16(af, bvA2, acc[mf][2], 0, 0, 0);
        acc[mf][3] = __builtin_amdgcn_mfma_f32_16x16x32_bf16(af, bvA3, acc[mf][3], 0, 0, 0);
      }
      __builtin_amdgcn_s_setprio(0);
    }
    // ---- odd half: tile tt+1 (A buf (tt+1)%3, B in bvB) ----
    VMW(2); BARR; FEN;
    {
      bf16_t* cur = lds + ((tt + 1) % 3) * 8192;
      const int kB = ((tt + 2 < nt ? tt + 2 : 0) << 5);
      bvA0 = *reinterpret_cast<const bf16x8*>(bp + 0l * 16 * ldb + kB);
      bvA1 = *reinterpret_cast<const bf16x8*>(bp + 1l * 16 * ldb + kB);
      bvA2 = *reinterpret_cast<const bf16x8*>(bp + 2l * 16 * ldb + kB);
      bvA3 = *reinterpret_cast<const bf16x8*>(bp + 3l * 16 * ldb + kB);
      FEN;
      const int kA = ((tt + 3 < nt ? tt + 3 : 0) << 5);
      bf16_t* nA = lds + ((tt + 3) % 3) * 8192;
      async16(A + kA + srcA[0], nA + t * 8);
      async16(A + kA + srcA[1], nA + 4096 + t * 8);
      FEN;
      __builtin_amdgcn_s_setprio(1);
#pragma unroll
      for (int mf = 0; mf < 4; ++mf) {
        bf16x8 af = *reinterpret_cast<const bf16x8*>(&cur[aOff[mf]]);
        acc[mf][0] = __builtin_amdgcn_mfma_f32_16x16x32_bf16(af, bvB0, acc[mf][0], 0, 0, 0);
        acc[mf][1] = __builtin_amdgcn_mfma_f32_16x16x32_bf16(af, bvB1, acc[mf][1], 0, 0, 0);
        acc[mf][2] = __builtin_amdgcn_mfma_f32_16x16x32_bf16(af, bvB2, acc[mf][2], 0, 0, 0);
        acc[mf][3] = __builtin_amdgcn_mfma_f32_16x16x32_bf16(af, bvB3, acc[mf][3], 0, 0, 0);
      }
      __builtin_amdgcn_s_setprio(0);
    }
  }
  VMW0;
  BARR; FEN;
}

// --- fused prep: z<4: W{q,k,v,g} transpose; z==4: Wo transpose; z==5: hs cvt
__global__ void k_prep(const float* __restrict__ hs, const float* __restrict__ W0,
                       const float* __restrict__ W1, const float* __restrict__ W2,
                       const float* __restrict__ W3, const float* __restrict__ Wo,
                       bf16_t* __restrict__ hsb, bf16_t* __restrict__ Wt4,
                       bf16_t* __restrict__ Wot) {
  int z = blockIdx.z;
  int t = threadIdx.x;
  if (z == 5) {
    const float4* in4 = (const float4*)hs;
    bf16x4* out4 = (bf16x4*)hsb;
    int base = (blockIdx.y * 32 + blockIdx.x) * 256 + t;
#pragma unroll
    for (int j = 0; j < 8; ++j) {
      int i = base + j * 262144;
      float4 v = in4[i];
      bf16x4 o;
      o[0] = (bf16_t)v.x; o[1] = (bf16_t)v.y; o[2] = (bf16_t)v.z; o[3] = (bf16_t)v.w;
      out4[i] = o;
    }
    return;
  }
  __shared__ bf16_t tile[64][65];
  int c = t & 63, r0 = t >> 6;
  if (z < 4) {
    if (blockIdx.y >= 16) return;
    const float* in = z == 0 ? W0 : z == 1 ? W1 : z == 2 ? W2 : W3;
    bf16_t* o = Wt4 + (long)z * DD * HID;
    int bc = blockIdx.x, br = blockIdx.y;
#pragma unroll
    for (int rr = 0; rr < 64; rr += 4) {
      int r = rr + r0;
      tile[r][c] = (bf16_t)in[(long)(br * 64 + r) * DD + bc * 64 + c];
    }
    __syncthreads();
#pragma unroll
    for (int rr = 0; rr < 64; rr += 4) {
      int r = rr + r0;
      o[(long)(bc * 64 + r) * HID + br * 64 + c] = tile[c][r];
    }
  } else {
    if (blockIdx.x >= 16) return;
    int bc = blockIdx.x, br = blockIdx.y;
#pragma unroll
    for (int rr = 0; rr < 64; rr += 4) {
      int r = rr + r0;
      tile[r][c] = (bf16_t)Wo[(long)(br * 64 + r) * HID + bc * 64 + c];
    }
    __syncthreads();
#pragma unroll
    for (int rr = 0; rr < 64; rr += 4) {
      int r = rr + r0;
      Wot[(long)(bc * 64 + r) * DD + br * 64 + c] = tile[c][r];
    }
  }
}

// --- GEMM1 (coreHB): QKVG = hsb @ Wt^T + bias; sigmoid z==3; z==2 -> Vt -----
__global__ __launch_bounds__(512, 4) void k_gemm_qkvg(
    const bf16_t* __restrict__ hsb, const bf16_t* __restrict__ Wt4,
    const float* __restrict__ bq, const float* __restrict__ bk,
    const float* __restrict__ bv, const float* __restrict__ bg,
    bf16_t* __restrict__ out, bf16_t* __restrict__ Vt) {
  extern __shared__ bf16_t lds[];
  const int SP = 136;   // row-major staging stride
  const int SPT = 264;  // transposed staging stride
  int i = blockIdx.x;
  int xcd = i & 7, g = i >> 3;
  int mb = g >> 3;             // 0..31 (256-row tiles)
  int nb = xcd * 8 + (g & 7);  // 0..63 (128-col tiles)
  f32x4 acc[4][4];
  coreHB(hsb + (long)mb * 256 * HID, HID, Wt4 + (long)nb * 128 * HID, HID,
         HID / 32, lds, acc);
  const int t = threadIdx.x, lane = t & 63, w = t >> 6;
  const int wm = w >> 1, wn = w & 1, lr = lane & 15, lg = lane >> 4;
  int z = nb >> 4;
  const float* bias = z == 0 ? bq : z == 1 ? bk : z == 2 ? bv : bg;
  int colT = (nb & 15) * 128;
  float b4[4];
#pragma unroll
  for (int nf = 0; nf < 4; ++nf) b4[nf] = bias[colT + wn * 64 + nf * 16 + lr];
  if (z != 2) {
#pragma unroll
    for (int mf = 0; mf < 4; ++mf)
#pragma unroll
      for (int reg = 0; reg < 4; ++reg) {
        int lrow = wm * 64 + mf * 16 + lg * 4 + reg;
#pragma unroll
        for (int nf = 0; nf < 4; ++nf) {
          float v = acc[mf][nf][reg] + b4[nf];
          if (z == 3) v = 1.f / (1.f + __expf(-v));
          lds[lrow * SP + wn * 64 + nf * 16 + lr] = (bf16_t)v;
        }
      }
    __syncthreads();
    bf16_t* O = out + (long)z * BS * DD + (long)mb * 256 * DD + colT;
#pragma unroll
    for (int it = 0; it < 8; ++it) {
      int s = it * 512 + t;
      int row = s >> 4, sg = s & 15;
      bf16x8 v = *reinterpret_cast<const bf16x8*>(&lds[row * SP + sg * 8]);
      *reinterpret_cast<bf16x8*>(&O[(long)row * DD + sg * 8]) = v;
    }
  } else {
    // TRANSPOSED staging (128 x 264): ldsT[d][s]
#pragma unroll
    for (int mf = 0; mf < 4; ++mf)
#pragma unroll
      for (int reg = 0; reg < 4; ++reg) {
        int lrow = wm * 64 + mf * 16 + lg * 4 + reg;
#pragma unroll
        for (int nf = 0; nf < 4; ++nf) {
          int d = wn * 64 + nf * 16 + lr;
          lds[d * SPT + lrow] = (bf16_t)(acc[mf][nf][reg] + b4[nf]);
        }
      }
    __syncthreads();
    int bz = mb >> 4, smb = mb & 15;
    bf16_t* Vd = Vt + ((long)bz * DD + colT) * SEQ + smb * 256;
#pragma unroll
    for (int it = 0; it < 8; ++it) {
      int s = it * 512 + t;
      int d = s >> 5, sg = s & 31;
      bf16x8 v = *reinterpret_cast<const bf16x8*>(&lds[d * SPT + sg * 8]);
      *reinterpret_cast<bf16x8*>(&Vd[(long)d * SEQ + sg * 8]) = v;
    }
  }
}

// --- pair (coreTB<2,4>): fused diag softmax ---------------------------------
__global__ __launch_bounds__(512, 4) void k_pair(const bf16_t* __restrict__ Q,
                                                 const bf16_t* __restrict__ Kb,
                                                 bf16_t* __restrict__ P) {
  extern __shared__ bf16_t lds[];
  int p = blockIdx.x, b = blockIdx.y;
  int c = 0, base = 0;
  while (base + (c >> 1) + 1 <= p) { base += (c >> 1) + 1; ++c; }
  int jt = p - base;  // jt in [0, (c>>1)]
  f32x4 acc[4][4];
  coreTB<2, 4>(Q + ((long)b * SEQ + (long)c * 128) * DD, DD,
               Kb + ((long)b * SEQ + (long)jt * 256) * DD, DD, DD / 32, lds, acc);
  const int t = threadIdx.x, lane = t & 63, w = t >> 6;
  const int wm = w >> 2, wn = w & 3, lr = lane & 15, lg = lane >> 4;
  bf16_t* Pt = P + ((long)b * SEQ + (long)c * 128) * (long)SEQ + (long)jt * 256;
  const bool hasDiag = (jt == (c >> 1));
  const int side = c & 1;
  const float scale = 0.02209708691207961f;  // 1/sqrt(2048)
  float* smf = (float*)lds;  // core quiesced LDS
#pragma unroll
  for (int mf = 0; mf < 4; ++mf)
#pragma unroll
    for (int reg = 0; reg < 4; ++reg) {
      int row = wm * 64 + mf * 16 + lg * 4 + reg;
#pragma unroll
      for (int nf = 0; nf < 4; ++nf) {
        int col = wn * 64 + nf * 16 + lr;
        float v = acc[mf][nf][reg];
        if (hasDiag && ((col >> 7) == side)) {
          int cc = col & 127;
          float sv = v * scale;
          smf[row * 128 + ((cc + row) & 127)] = (cc <= row) ? sv : -1e30f;
        } else {
          if (hasDiag && side == 0 && (col >> 7) == 1) v = 0.f;  // future chunk
          Pt[(long)row * SEQ + col] = (bf16_t)v;
        }
      }
    }
  if (hasDiag) {
    __syncthreads();
    if (t < 128) {
      int r = t;
      float mx = -1e30f;
      for (int cc = 0; cc <= r; ++cc) mx = fmaxf(mx, smf[r * 128 + ((cc + r) & 127)]);
      float s = 0.f;
      for (int cc = 0; cc <= r; ++cc) s += __expf(smf[r * 128 + ((cc + r) & 127)] - mx);
      float inv = 1.f / s;
      for (int cc = 0; cc < 128; ++cc) {
        float v = (cc <= r) ? __expf(smf[r * 128 + ((cc + r) & 127)] - mx) * inv : 0.f;
        Pt[(long)r * SEQ + side * 128 + cc] = (bf16_t)v;
      }
    }
  }
}

// --- GEMM2 (coreTB<2,4>, XCD-pinned nb): OutPre = (P @ V[0:K]) * gate -------
__global__ __launch_bounds__(512, 4) void k_gemm2(const bf16_t* __restrict__ P,
                                                  const bf16_t* __restrict__ Vt,
                                                  const bf16_t* __restrict__ G,
                                                  bf16_t* __restrict__ OutPre) {
  extern __shared__ bf16_t lds[];
  int bid = blockIdx.x;
  int nb = bid & 7;          // XCD-pinned
  int tmp = bid >> 3;        // 0..63
  int mq = 31 - (tmp >> 1);  // longest-first within XCD
  int b = tmp & 1;
  f32x4 acc[4][4];
  coreTB<2, 4>(P + ((long)b * SEQ + (long)mq * 128) * (long)SEQ, SEQ,
               Vt + (long)b * DD * SEQ + (long)nb * 256 * SEQ, SEQ, (mq + 1) * 4,
               lds, acc);
  const int t = threadIdx.x, lane = t & 63, w = t >> 6;
  const int wm = w >> 2, wn = w & 3, lr = lane & 15, lg = lane >> 4;
#pragma unroll
  for (int mf = 0; mf < 4; ++mf)
#pragma unroll
    for (int reg = 0; reg < 4; ++reg) {
      long row = (long)b * SEQ + (long)mq * 128 + wm * 64 + mf * 16 + lg * 4 + reg;
#pragma unroll
      for (int nf = 0; nf < 4; ++nf) {
        long idx = row * DD + nb * 256 + wn * 64 + nf * 16 + lr;
        float g = (float)G[idx];
        OutPre[idx] = (bf16_t)(acc[mf][nf][reg] * g);
      }
    }
}

// --- GEMM3 (coreTB<2,4>): out = OutPre @ Wo + bo ----------------------------
__global__ __launch_bounds__(512, 4) void k_gemm3(const bf16_t* __restrict__ OutPre,
                                                  const bf16_t* __restrict__ Wot,
                                                  const float* __restrict__ bo,
                                                  float* __restrict__ out) {
  extern __shared__ bf16_t lds[];
  int mb = blockIdx.x >> 2, nb = blockIdx.x & 3;
  f32x4 acc[4][4];
  coreTB<2, 4>(OutPre + (long)mb * 128 * DD, DD, Wot + (long)nb * 256 * DD, DD,
               DD / 32, lds, acc);
  const int t = threadIdx.x, lane = t & 63, w = t >> 6;
  const int wm = w >> 2, wn = w & 3, lr = lane & 15, lg = lane >> 4;
  int colbase = nb * 256 + wn * 64;
  float b4[4];
#pragma unroll
  for (int nf = 0; nf < 4; ++nf) b4[nf] = bo[colbase + nf * 16 + lr];
#pragma unroll
  for (int mf = 0; mf < 4; ++mf)
#pragma unroll
    for (int reg = 0; reg < 4; ++reg) {
      long row = mb * 128 + wm * 64 + mf * 16 + lg * 4 + reg;
#pragma unroll
      for (int nf = 0; nf < 4; ++nf)
        out[row * HID + colbase + nf * 16 + lr] = acc[mf][nf][reg] + b4[nf];
    }
}

extern "C" void kernel_launch(void* const* d_in, const int* in_sizes, int n_in,
                              void* d_out, int out_size, void* d_ws, size_t ws_size,
                              hipStream_t stream) {
  const float* hs = (const float*)d_in[0];
  const float* Wq = (const float*)d_in[1];
  const float* bq = (const float*)d_in[2];
  const float* Wk = (const float*)d_in[3];
  const float* bk = (const float*)d_in[4];
  const float* Wv = (const float*)d_in[5];
  const float* bv = (const float*)d_in[6];
  const float* Wg = (const float*)d_in[7];
  const float* bg = (const float*)d_in[8];
  const float* Wo = (const float*)d_in[9];
  const float* bo = (const float*)d_in[10];
  float* out = (float*)d_out;

  char* ws = (char*)d_ws;
  const size_t MB = 1024 * 1024;
  bf16_t* P = (bf16_t*)(ws);            // [2][4096][4096] bf16, 64MB
  bf16_t* hsb = (bf16_t*)(ws);          // aliases P (dead before pair)
  bf16_t* Wt4 = (bf16_t*)(ws + 16 * MB);
  bf16_t* Wot = (bf16_t*)(ws + 64 * MB);
  bf16_t* QKVG = (bf16_t*)(ws + 68 * MB);
  bf16_t* Vt = (bf16_t*)(ws + 196 * MB);

  bf16_t* Qb = QKVG;
  bf16_t* Kbuf = QKVG + (long)BS * DD;
  bf16_t* Vbuf = QKVG + 2l * BS * DD;  // V row-major unused (V -> Vt directly)
  bf16_t* Gbuf = QKVG + 3l * BS * DD;
  bf16_t* OutPre = Vbuf;

  hipFuncSetAttribute((const void*)k_gemm_qkvg,
                      hipFuncAttributeMaxDynamicSharedMemorySize, LDS_HB);
  hipFuncSetAttribute((const void*)k_pair,
                      hipFuncAttributeMaxDynamicSharedMemorySize, LDS_TB);
  hipFuncSetAttribute((const void*)k_gemm2,
                      hipFuncAttributeMaxDynamicSharedMemorySize, LDS_TB);
  hipFuncSetAttribute((const void*)k_gemm3,
                      hipFuncAttributeMaxDynamicSharedMemorySize, LDS_TB);

  // 1. fused prep (hs cvt + Wq/Wk/Wv/Wg/Wo transposes)
  k_prep<<<dim3(32, 32, 6), 256, 0, stream>>>(hs, Wq, Wk, Wv, Wg, Wo, hsb, Wt4, Wot);

  // 2. QKVG projection (coreHB: A in LDS, B direct->reg; V fused -> Vt)
  k_gemm_qkvg<<<2048, 512, LDS_HB, stream>>>(hsb, Wt4, bq, bk, bv, bg, QKVG, Vt);

  // 3. pairwise scores + fused diag softmax (544 blocks, 2 blk/CU)
  k_pair<<<dim3(272, 2), 512, LDS_TB, stream>>>(Qb, Kbuf, P);

  // 4. PV + gate (512 blocks; nb XCD-pinned, longest-first, 2 blk/CU)
  k_gemm2<<<512, 512, LDS_TB, stream>>>(P, Vt, Gbuf, OutPre);

  // 5. output projection (256 blocks, 2 blk/CU)
  k_gemm3<<<256, 512, LDS_TB, stream>>>(OutPre, Wot, bo, out);
}

// Round 17
// 421.280 us; speedup vs baseline: 1.3275x; 1.3275x over previous
//
#include <hip/hip_runtime.h>
#include <hip/hip_bf16.h>
#include <math.h>

// ---------------------------------------------------------------------------
// ChunkGatedAttentionUnit: B=2, S=4096, H=1024, D=2048, CHUNK=128, nC=32
// Round 17: restore round-11 kernel verbatim (session best, 422.46 us).
//   - qkvg: coreK32<4,2> (2 blk/CU, fused V->Vt transposed staging)
//   - pair/gemm2/gemm3: core128 2-sync kernels
// R16's B-direct-to-reg regressed (exposed global latency); reverted.
// ---------------------------------------------------------------------------

typedef __bf16 bf16_t;
typedef __bf16 bf16x8 __attribute__((ext_vector_type(8)));
typedef __bf16 bf16x4 __attribute__((ext_vector_type(4)));
typedef float f32x4 __attribute__((ext_vector_type(4)));

#define NB_ 2
#define SEQ 4096
#define HID 1024
#define DD 2048
#define BS 8192
#define LDS_128 98304   // core128 dbuf: 2 x (16KB A + 32KB B)
#define LDS_QKVG 69632  // max(coreK32<4,2> dbuf 49152, staging 256*136*2)

__device__ __forceinline__ void async16(const void* g, void* l) {
  __builtin_amdgcn_global_load_lds(
      (const __attribute__((address_space(1))) void*)g,
      (__attribute__((address_space(3))) void*)l, 16, 0, 0);
}

#define VMW(n) asm volatile("s_waitcnt vmcnt(" #n ")" ::: "memory")
#define VMW0 asm volatile("s_waitcnt vmcnt(0)" ::: "memory")
#define BARR __builtin_amdgcn_s_barrier()
#define FEN asm volatile("" ::: "memory")

// ===== R3's BM=128 x BN=256 core (2 counted-vmcnt syncs per K-tile) =========
template <int MFH>
__device__ __forceinline__ void readA8(const bf16_t* bufA, int aBase, int s0, int s1,
                                       bf16x8 (&af)[4][2]) {
#pragma unroll
  for (int mm = 0; mm < 4; ++mm) {
    int p = aBase + MFH * 8192 + mm * 1024;
    af[mm][0] = *reinterpret_cast<const bf16x8*>(&bufA[p + s0]);
    af[mm][1] = *reinterpret_cast<const bf16x8*>(&bufA[p + s1]);
  }
}
template <int NFH>
__device__ __forceinline__ void readB4(const bf16_t* bufB, int bBase, int s0, int s1,
                                       bf16x8 (&bv)[2][2]) {
#pragma unroll
  for (int nn = 0; nn < 2; ++nn) {
    int p = bBase + NFH * 8192 + nn * 1024;
    bv[nn][0] = *reinterpret_cast<const bf16x8*>(&bufB[p + s0]);
    bv[nn][1] = *reinterpret_cast<const bf16x8*>(&bufB[p + s1]);
  }
}
template <int MROWS, int MQ, int NQ>
__device__ __forceinline__ void mfmaQ(const bf16x8 (&af)[4][2], const bf16x8 (&bv)[2][2],
                                      f32x4 (&acc)[MROWS][4]) {
  __builtin_amdgcn_s_setprio(1);
#pragma unroll
  for (int kki = 0; kki < 2; ++kki)
#pragma unroll
    for (int mm = 0; mm < 4; ++mm)
#pragma unroll
      for (int nn = 0; nn < 2; ++nn)
        acc[MQ * 4 + mm][NQ * 2 + nn] = __builtin_amdgcn_mfma_f32_16x16x32_bf16(
            af[mm][kki], bv[nn][kki], acc[MQ * 4 + mm][NQ * 2 + nn], 0, 0, 0);
  __builtin_amdgcn_s_setprio(0);
}

__device__ __forceinline__ void core128(const bf16_t* __restrict__ A, int lda,
                                        const bf16_t* __restrict__ B, int ldb, int nt,
                                        bf16_t* lds, f32x4 (&acc)[4][4]) {
  const int t = threadIdx.x;
  const int lane = t & 63, w = t >> 6;
  const int wm = w >> 2, wn = w & 3;
  const int lr = lane & 15, lg = lane >> 4;
  const int xm = lr & 7;
  const int aBase = (wm * 64 + lr) * 64;
  const int bBase = (wn * 32 + lr) * 64;
  const int s0 = (lg ^ xm) * 8, s1 = ((4 + lg) ^ xm) * 8;
  const int slog = ((t & 7) ^ ((t >> 3) & 7)) * 8;
  int srcA[2], srcB[4];
#pragma unroll
  for (int blk = 0; blk < 2; ++blk) srcA[blk] = (blk * 64 + (t >> 3)) * lda + slog;
#pragma unroll
  for (int blk = 0; blk < 4; ++blk) {
    int prB = (blk << 6) + (t >> 3);
    int rB = (((prB >> 5) & 3) << 6) + ((prB >> 7) << 5) + (prB & 31);
    srcB[blk] = rB * ldb + slog;
  }
  const int dstT = t * 8;
#pragma unroll
  for (int m = 0; m < 4; ++m)
#pragma unroll
    for (int n = 0; n < 4; ++n) acc[m][n] = (f32x4){0.f, 0.f, 0.f, 0.f};

  {  // prologue: order A0,A1,B0,B1,B2,B3
    bf16_t* nA = lds;
    bf16_t* nB = lds + 8192;
    async16(A + srcA[0], nA + dstT);
    async16(A + srcA[1], nA + 4096 + dstT);
    async16(B + srcB[0], nB + dstT);
    async16(B + srcB[1], nB + 4096 + dstT);
    async16(B + srcB[2], nB + 8192 + dstT);
    async16(B + srcB[3], nB + 12288 + dstT);
  }
  bf16x8 af[4][2], bv0[2][2], bv1[2][2];
  for (int kt = 0; kt < nt; ++kt) {
    bf16_t* bufA = lds + (kt & 1) * 24576;
    bf16_t* bufB = bufA + 8192;
    bf16_t* nA = lds + ((kt + 1) & 1) * 24576;
    bf16_t* nB = nA + 8192;
    const int kn = (kt + 1 < nt ? kt + 1 : 0) << 6;
    const bf16_t* An = A + kn;
    const bf16_t* Bn = B + kn;
    VMW(2); BARR; FEN;
    readA8<0>(bufA, aBase, s0, s1, af);
    readB4<0>(bufB, bBase, s0, s1, bv0);
    async16(An + srcA[0], nA + dstT);
    async16(An + srcA[1], nA + 4096 + dstT);
    async16(Bn + srcB[0], nB + dstT);
    mfmaQ<4, 0, 0>(af, bv0, acc);
    VMW(3); BARR; FEN;
    readB4<1>(bufB, bBase, s0, s1, bv1);
    async16(Bn + srcB[1], nB + 4096 + dstT);
    async16(Bn + srcB[2], nB + 8192 + dstT);
    async16(Bn + srcB[3], nB + 12288 + dstT);
    mfmaQ<4, 0, 1>(af, bv1, acc);
  }
  VMW0;
  BARR;
}

// ===== R7's BK=32 core (qkvg: 2 blocks/CU) ==================================
template <int WM, int WN>
__device__ __forceinline__ void coreK32(const bf16_t* __restrict__ A, int lda,
                                        const bf16_t* __restrict__ B, int ldb, int nt,
                                        bf16_t* lds, f32x4 (&acc)[4][4]) {
  constexpr int T = WM * WN * 64;
  constexpr int AE = WM * 64 * 32;
  constexpr int BUF = AE + WN * 64 * 32;
  constexpr int NISS = BUF / (T * 8);
  const int t = threadIdx.x;
  const int lane = t & 63, w = t >> 6;
  const int wm = w / WN, wn = w % WN;
  const int lr = lane & 15, lg = lane >> 4;

  int aOff[4], bOff[4];
#pragma unroll
  for (int f = 0; f < 4; ++f) {
    int ra = wm * 64 + f * 16 + lr;
    aOff[f] = ra * 32 + (((lg + (ra >> 1)) & 3) << 3);
    int rb = wn * 64 + f * 16 + lr;
    bOff[f] = AE + rb * 32 + (((lg + (rb >> 1)) & 3) << 3);
  }
  int src[NISS];
#pragma unroll
  for (int q = 0; q < NISS; ++q) {
    int e = q * T * 8 + t * 8;
    bool isB = (q * T * 8) >= AE;
    int e2 = isB ? e - AE : e;
    int r = e2 >> 5;
    int g = (((e2 >> 3) & 3) - (r >> 1)) & 3;
    src[q] = r * (isB ? ldb : lda) + g * 8;
  }
#pragma unroll
  for (int m = 0; m < 4; ++m)
#pragma unroll
    for (int n = 0; n < 4; ++n) acc[m][n] = (f32x4){0.f, 0.f, 0.f, 0.f};

  {
    bf16_t* buf0 = lds;
#pragma unroll
    for (int q = 0; q < NISS; ++q) {
      bool isB = (q * T * 8) >= AE;
      async16((isB ? B : A) + src[q], buf0 + q * T * 8 + t * 8);
    }
  }
  VMW0; BARR; FEN;

  for (int tt = 0; tt < nt; ++tt) {
    bf16_t* cur = lds + (tt & 1) * BUF;
    bf16_t* nxt = lds + ((tt + 1) & 1) * BUF;
    const int kn = (tt + 1 < nt ? tt + 1 : 0) << 5;
#pragma unroll
    for (int q = 0; q < NISS; ++q) {
      bool isB = (q * T * 8) >= AE;
      async16((isB ? B : A) + kn + src[q], nxt + q * T * 8 + t * 8);
    }
    bf16x8 af[4], bv[4];
#pragma unroll
    for (int f = 0; f < 4; ++f) af[f] = *reinterpret_cast<const bf16x8*>(&cur[aOff[f]]);
#pragma unroll
    for (int f = 0; f < 4; ++f) bv[f] = *reinterpret_cast<const bf16x8*>(&cur[bOff[f]]);
    __builtin_amdgcn_s_setprio(1);
#pragma unroll
    for (int mf = 0; mf < 4; ++mf)
#pragma unroll
      for (int nf = 0; nf < 4; ++nf)
        acc[mf][nf] =
            __builtin_amdgcn_mfma_f32_16x16x32_bf16(af[mf], bv[nf], acc[mf][nf], 0, 0, 0);
    __builtin_amdgcn_s_setprio(0);
    VMW0; BARR; FEN;
  }
}

// --- elementwise convert f32 -> bf16 ---------------------------------------
__global__ void k_cvt(const float4* __restrict__ in, bf16x4* __restrict__ out, int n4) {
  int i = blockIdx.x * blockDim.x + threadIdx.x;
  if (i < n4) {
    float4 v = in[i];
    bf16x4 o;
    o[0] = (bf16_t)v.x; o[1] = (bf16_t)v.y; o[2] = (bf16_t)v.z; o[3] = (bf16_t)v.w;
    out[i] = o;
  }
}

// --- tiled transpose + convert f32[R][C] -> bf16[C][R] ----------------------
__global__ void k_tconv(const float* __restrict__ in, bf16_t* __restrict__ out,
                        int R, int C) {
  __shared__ bf16_t tile[64][65];
  int bc = blockIdx.x, br = blockIdx.y;
  int t = threadIdx.x;
  int c = t & 63, r0 = t >> 6;
#pragma unroll
  for (int rr = 0; rr < 64; rr += 4) {
    int r = rr + r0;
    tile[r][c] = (bf16_t)in[(long)(br * 64 + r) * C + bc * 64 + c];
  }
  __syncthreads();
#pragma unroll
  for (int rr = 0; rr < 64; rr += 4) {
    int r = rr + r0;
    out[(long)(bc * 64 + r) * R + br * 64 + c] = tile[c][r];
  }
}

// --- GEMM1: QKVG = hsb @ Wt^T + bias; sigmoid z==3; z==2 -> Vt (transposed) -
// tile 256x128 (coreK32<4,2>). grid 2048: xcd=i&7, g=i>>3.
__global__ __launch_bounds__(512, 4) void k_gemm_qkvg(
    const bf16_t* __restrict__ hsb, const bf16_t* __restrict__ Wt4,
    const float* __restrict__ bq, const float* __restrict__ bk,
    const float* __restrict__ bv, const float* __restrict__ bg,
    bf16_t* __restrict__ out, bf16_t* __restrict__ Vt) {
  extern __shared__ bf16_t lds[];
  const int SP = 136;   // row-major staging stride
  const int SPT = 264;  // transposed staging stride
  int i = blockIdx.x;
  int xcd = i & 7, g = i >> 3;
  int mb = g >> 3;             // 0..31 (256-row tiles)
  int nb = xcd * 8 + (g & 7);  // 0..63 (128-col tiles)
  f32x4 acc[4][4];
  coreK32<4, 2>(hsb + (long)mb * 256 * HID, HID, Wt4 + (long)nb * 128 * HID, HID,
                HID / 32, lds, acc);
  const int t = threadIdx.x, lane = t & 63, w = t >> 6;
  const int wm = w >> 1, wn = w & 1, lr = lane & 15, lg = lane >> 4;
  int z = nb >> 4;
  const float* bias = z == 0 ? bq : z == 1 ? bk : z == 2 ? bv : bg;
  int colT = (nb & 15) * 128;
  float b4[4];
#pragma unroll
  for (int nf = 0; nf < 4; ++nf) b4[nf] = bias[colT + wn * 64 + nf * 16 + lr];
  if (z != 2) {
    // row-major staging (256 x 136)
#pragma unroll
    for (int mf = 0; mf < 4; ++mf)
#pragma unroll
      for (int reg = 0; reg < 4; ++reg) {
        int lrow = wm * 64 + mf * 16 + lg * 4 + reg;
#pragma unroll
        for (int nf = 0; nf < 4; ++nf) {
          float v = acc[mf][nf][reg] + b4[nf];
          if (z == 3) v = 1.f / (1.f + __expf(-v));
          lds[lrow * SP + wn * 64 + nf * 16 + lr] = (bf16_t)v;
        }
      }
    __syncthreads();
    bf16_t* O = out + (long)z * BS * DD + (long)mb * 256 * DD + colT;
#pragma unroll
    for (int it = 0; it < 8; ++it) {
      int s = it * 512 + t;
      int row = s >> 4, sg = s & 15;
      bf16x8 v = *reinterpret_cast<const bf16x8*>(&lds[row * SP + sg * 8]);
      *reinterpret_cast<bf16x8*>(&O[(long)row * DD + sg * 8]) = v;
    }
  } else {
    // TRANSPOSED staging (128 x 264): ldsT[d][s]; write-bank stride 4 (free)
#pragma unroll
    for (int mf = 0; mf < 4; ++mf)
#pragma unroll
      for (int reg = 0; reg < 4; ++reg) {
        int lrow = wm * 64 + mf * 16 + lg * 4 + reg;
#pragma unroll
        for (int nf = 0; nf < 4; ++nf) {
          int d = wn * 64 + nf * 16 + lr;
          lds[d * SPT + lrow] = (bf16_t)(acc[mf][nf][reg] + b4[nf]);
        }
      }
    __syncthreads();
    int bz = mb >> 4, smb = mb & 15;
    bf16_t* Vd = Vt + ((long)bz * DD + colT) * SEQ + smb * 256;
    // copy-out: 128 d-rows x 512B, b128 reads (row-major in ldsT) — clean
#pragma unroll
    for (int it = 0; it < 8; ++it) {
      int s = it * 512 + t;
      int d = s >> 5, sg = s & 31;
      bf16x8 v = *reinterpret_cast<const bf16x8*>(&lds[d * SPT + sg * 8]);
      *reinterpret_cast<bf16x8*>(&Vd[(long)d * SEQ + sg * 8]) = v;
    }
  }
}

// --- pair (R3): P[row-chunk c][jt-tile] = Q K^T; fused diag softmax ---------
__global__ __launch_bounds__(512, 2) void k_pair(const bf16_t* __restrict__ Q,
                                                 const bf16_t* __restrict__ Kb,
                                                 bf16_t* __restrict__ P) {
  extern __shared__ bf16_t lds[];
  int p = blockIdx.x, b = blockIdx.y;
  int c = 0, base = 0;
  while (base + (c >> 1) + 1 <= p) { base += (c >> 1) + 1; ++c; }
  int jt = p - base;  // jt in [0, (c>>1)]
  f32x4 acc[4][4];
  core128(Q + ((long)b * SEQ + (long)c * 128) * DD, DD,
          Kb + ((long)b * SEQ + (long)jt * 256) * DD, DD, DD / 64, lds, acc);
  const int t = threadIdx.x, lane = t & 63, w = t >> 6;
  const int wm = w >> 2, wn = w & 3, lr = lane & 15, lg = lane >> 4;
  bf16_t* Pt = P + ((long)b * SEQ + (long)c * 128) * (long)SEQ + (long)jt * 256;
  const bool hasDiag = (jt == (c >> 1));
  const int side = c & 1;
  const float scale = 0.02209708691207961f;  // 1/sqrt(2048)
  float* smf = (float*)lds;  // core quiesced LDS
#pragma unroll
  for (int mf = 0; mf < 4; ++mf)
#pragma unroll
    for (int reg = 0; reg < 4; ++reg) {
      int row = wm * 64 + mf * 16 + lg * 4 + reg;
#pragma unroll
      for (int nf = 0; nf < 4; ++nf) {
        int col = wn * 64 + nf * 16 + lr;
        float v = acc[mf][nf][reg];
        if (hasDiag && ((col >> 7) == side)) {
          int cc = col & 127;
          float sv = v * scale;
          smf[row * 128 + ((cc + row) & 127)] = (cc <= row) ? sv : -1e30f;
        } else {
          if (hasDiag && side == 0 && (col >> 7) == 1) v = 0.f;  // future chunk
          Pt[(long)row * SEQ + col] = (bf16_t)v;
        }
      }
    }
  if (hasDiag) {
    __syncthreads();
    if (t < 128) {
      int r = t;
      float mx = -1e30f;
      for (int cc = 0; cc <= r; ++cc) mx = fmaxf(mx, smf[r * 128 + ((cc + r) & 127)]);
      float s = 0.f;
      for (int cc = 0; cc <= r; ++cc) s += __expf(smf[r * 128 + ((cc + r) & 127)] - mx);
      float inv = 1.f / s;
      for (int cc = 0; cc < 128; ++cc) {
        float v = (cc <= r) ? __expf(smf[r * 128 + ((cc + r) & 127)] - mx) * inv : 0.f;
        Pt[(long)r * SEQ + side * 128 + cc] = (bf16_t)v;
      }
    }
  }
}

// --- GEMM2 (R3): OutPre = (P @ V[0:K]) * gate, BM=128, longest-first --------
__global__ __launch_bounds__(512, 2) void k_gemm2(const bf16_t* __restrict__ P,
                                                  const bf16_t* __restrict__ Vt,
                                                  const bf16_t* __restrict__ G,
                                                  bf16_t* __restrict__ OutPre) {
  extern __shared__ bf16_t lds[];
  int bid = blockIdx.x;
  int mq = 31 - (bid >> 4);  // longest-first
  int r2 = bid & 15;
  int nb = r2 >> 1, b = r2 & 1;
  f32x4 acc[4][4];
  core128(P + ((long)b * SEQ + (long)mq * 128) * (long)SEQ, SEQ,
          Vt + (long)b * DD * SEQ + (long)nb * 256 * SEQ, SEQ, (mq + 1) * 2, lds, acc);
  const int t = threadIdx.x, lane = t & 63, w = t >> 6;
  const int wm = w >> 2, wn = w & 3, lr = lane & 15, lg = lane >> 4;
#pragma unroll
  for (int mf = 0; mf < 4; ++mf)
#pragma unroll
    for (int reg = 0; reg < 4; ++reg) {
      long row = (long)b * SEQ + (long)mq * 128 + wm * 64 + mf * 16 + lg * 4 + reg;
#pragma unroll
      for (int nf = 0; nf < 4; ++nf) {
        long idx = row * DD + nb * 256 + wn * 64 + nf * 16 + lr;
        float g = (float)G[idx];
        OutPre[idx] = (bf16_t)(acc[mf][nf][reg] * g);
      }
    }
}

// --- GEMM3 (R3): out = OutPre @ Wo + bo (f32 out), BM=128 -------------------
__global__ __launch_bounds__(512, 2) void k_gemm3(const bf16_t* __restrict__ OutPre,
                                                  const bf16_t* __restrict__ Wot,
                                                  const float* __restrict__ bo,
                                                  float* __restrict__ out) {
  extern __shared__ bf16_t lds[];
  int mb = blockIdx.x >> 2, nb = blockIdx.x & 3;
  f32x4 acc[4][4];
  core128(OutPre + (long)mb * 128 * DD, DD, Wot + (long)nb * 256 * DD, DD,
          DD / 64, lds, acc);
  const int t = threadIdx.x, lane = t & 63, w = t >> 6;
  const int wm = w >> 2, wn = w & 3, lr = lane & 15, lg = lane >> 4;
  int colbase = nb * 256 + wn * 64;
  float b4[4];
#pragma unroll
  for (int nf = 0; nf < 4; ++nf) b4[nf] = bo[colbase + nf * 16 + lr];
#pragma unroll
  for (int mf = 0; mf < 4; ++mf)
#pragma unroll
    for (int reg = 0; reg < 4; ++reg) {
      long row = mb * 128 + wm * 64 + mf * 16 + lg * 4 + reg;
#pragma unroll
      for (int nf = 0; nf < 4; ++nf)
        out[row * HID + colbase + nf * 16 + lr] = acc[mf][nf][reg] + b4[nf];
    }
}

extern "C" void kernel_launch(void* const* d_in, const int* in_sizes, int n_in,
                              void* d_out, int out_size, void* d_ws, size_t ws_size,
                              hipStream_t stream) {
  const float* hs = (const float*)d_in[0];
  const float* Wq = (const float*)d_in[1];
  const float* bq = (const float*)d_in[2];
  const float* Wk = (const float*)d_in[3];
  const float* bk = (const float*)d_in[4];
  const float* Wv = (const float*)d_in[5];
  const float* bv = (const float*)d_in[6];
  const float* Wg = (const float*)d_in[7];
  const float* bg = (const float*)d_in[8];
  const float* Wo = (const float*)d_in[9];
  const float* bo = (const float*)d_in[10];
  float* out = (float*)d_out;

  char* ws = (char*)d_ws;
  const size_t MB = 1024 * 1024;
  bf16_t* P = (bf16_t*)(ws);            // [2][4096][4096] bf16, 64MB
  bf16_t* hsb = (bf16_t*)(ws);          // aliases P (dead before pair)
  bf16_t* Wt4 = (bf16_t*)(ws + 16 * MB);
  bf16_t* Wot = (bf16_t*)(ws + 64 * MB);
  bf16_t* QKVG = (bf16_t*)(ws + 68 * MB);
  bf16_t* Vt = (bf16_t*)(ws + 196 * MB);

  bf16_t* Qb = QKVG;
  bf16_t* Kbuf = QKVG + (long)BS * DD;
  bf16_t* Vbuf = QKVG + 2l * BS * DD;  // V row-major unused (V -> Vt directly)
  bf16_t* Gbuf = QKVG + 3l * BS * DD;
  bf16_t* OutPre = Vbuf;

  hipFuncSetAttribute((const void*)k_gemm_qkvg,
                      hipFuncAttributeMaxDynamicSharedMemorySize, LDS_QKVG);
  hipFuncSetAttribute((const void*)k_pair,
                      hipFuncAttributeMaxDynamicSharedMemorySize, LDS_128);
  hipFuncSetAttribute((const void*)k_gemm2,
                      hipFuncAttributeMaxDynamicSharedMemorySize, LDS_128);
  hipFuncSetAttribute((const void*)k_gemm3,
                      hipFuncAttributeMaxDynamicSharedMemorySize, LDS_128);

  // 1. conversions
  k_cvt<<<(BS * HID / 4 + 255) / 256, 256, 0, stream>>>((const float4*)hs,
                                                        (bf16x4*)hsb, BS * HID / 4);
  k_tconv<<<dim3(DD / 64, HID / 64), 256, 0, stream>>>(Wq, Wt4 + 0l * DD * HID, HID, DD);
  k_tconv<<<dim3(DD / 64, HID / 64), 256, 0, stream>>>(Wk, Wt4 + 1l * DD * HID, HID, DD);
  k_tconv<<<dim3(DD / 64, HID / 64), 256, 0, stream>>>(Wv, Wt4 + 2l * DD * HID, HID, DD);
  k_tconv<<<dim3(DD / 64, HID / 64), 256, 0, stream>>>(Wg, Wt4 + 3l * DD * HID, HID, DD);
  k_tconv<<<dim3(HID / 64, DD / 64), 256, 0, stream>>>(Wo, Wot, DD, HID);

  // 2. QKVG projection (2048 blocks, 2 blk/CU; V fused -> Vt transposed)
  k_gemm_qkvg<<<2048, 512, LDS_QKVG, stream>>>(hsb, Wt4, bq, bk, bv, bg, QKVG, Vt);

  // 3. pairwise scores + fused diag softmax (544 uniform 128x256 blocks)
  k_pair<<<dim3(272, 2), 512, LDS_128, stream>>>(Qb, Kbuf, P);

  // 4. PV + gate (512 blocks, longest-first)
  k_gemm2<<<512, 512, LDS_128, stream>>>(P, Vt, Gbuf, OutPre);

  // 5. output projection (256 blocks)
  k_gemm3<<<256, 512, LDS_128, stream>>>(OutPre, Wot, bo, out);
}